// Round 12
// baseline (156.887 us; speedup 1.0000x reference)
//
#include <hip/hip_runtime.h>
#include <hip/hip_bf16.h>

typedef float f32x4  __attribute__((ext_vector_type(4)));
typedef short bf16x8 __attribute__((ext_vector_type(8)));

__device__ __forceinline__ short bf16r(float x) {
    unsigned u = __builtin_bit_cast(unsigned, x);
    u += 0x7fffu + ((u >> 16) & 1u);
    return (short)(u >> 16);
}

// prepass: hs[b][l][i][k] = bf16(head[b][i][k] * U[l][k])  (128MB)
//          dp = bf16(dep)                                   (4MB)
__global__ void prep_kernel(const float* __restrict__ head, const float* __restrict__ dep,
                            const float* __restrict__ U,
                            short* __restrict__ hs, short* __restrict__ dp) {
    const int NH = 8 * 32 * 512 * 64;            // 8,388,608 hs-chunks of 8
    int gid = blockIdx.x * blockDim.x + threadIdx.x;
    if (gid < NH) {
        const int k8 = gid & 63;
        const int i  = (gid >> 6) & 511;
        const int l  = (gid >> 15) & 31;
        const int b  = gid >> 20;
        const float* hsrc = head + ((size_t)(b * 512 + i)) * 512 + k8 * 8;
        const float* usrc = U + (size_t)l * 512 + k8 * 8;
        f32x4 h0 = *(const f32x4*)hsrc,      h1 = *(const f32x4*)(hsrc + 4);
        f32x4 u0 = *(const f32x4*)usrc,      u1 = *(const f32x4*)(usrc + 4);
        bf16x8 v;
#pragma unroll
        for (int e = 0; e < 4; ++e) {
            v[e]     = bf16r(h0[e] * u0[e]);
            v[4 + e] = bf16r(h1[e] * u1[e]);
        }
        *(bf16x8*)(hs + (((size_t)(b * 32 + l) * 512 + i) * 512 + k8 * 8)) = v;
    } else {
        const int j = gid - NH;                  // < 262,144 dep-chunks
        f32x4 a = *(const f32x4*)(dep + (size_t)j * 8);
        f32x4 c = *(const f32x4*)(dep + (size_t)j * 8 + 4);
        bf16x8 v;
#pragma unroll
        for (int e = 0; e < 4; ++e) { v[e] = bf16r(a[e]); v[4 + e] = bf16r(c[e]); }
        *(bf16x8*)(dp + (size_t)j * 8) = v;
    }
}

// ---- main: PURE bf16 GEMM. 256x256 tile, 8 waves (2m x 4n, wave 128x64),
// BK=64, 4 phases/K-tile (16 MFMA each), dbuf LDS 128KB. Both operands via
// global_load_lds (A pre-scaled by U in prepass -> ZERO VALU in the loop).
// Staging spread over ph0/ph1 -> aged >=2 phases at the tile-end drain.
__global__ __launch_bounds__(512, 2)
void bla_gemm12(const short* __restrict__ hs,
                const short* __restrict__ dp,
                float* __restrict__ out)
{
    constexpr int S = 512, D = 512, L = 32, BM = 256, BN = 256, BK = 64, NT = 8;

    __shared__ __align__(16) short Al[2][BM * BK];   // 32KB each
    __shared__ __align__(16) short Bl[2][BN * BK];   // 32KB each -> 128KB

    const int tid = threadIdx.x, lane = tid & 63, wid = tid >> 6;
    const int wm = wid >> 2, wn = wid & 3;           // 2m x 4n, wave tile 128x64

    // XCD swizzle: 1024 blocks -> 128/XCD = one b per XCD.
    // it/ot outer, l inner: dep[b] ot-panel (256KB) stays L2-hot across 32 l's.
    const int swz = (blockIdx.x & 7) * ((int)gridDim.x >> 3) + (blockIdx.x >> 3);
    const int b = swz >> 7, rem = swz & 127;
    const int it = rem >> 6, ot = (rem >> 5) & 1, l = rem & 31;
    const int i0 = it * BM, o0 = ot * BN;

    // gload_lds: linear LDS dest, inverse-swizzled global source (rule #21)
    const int bso = ((lane & 7) * 16) ^ ((lane >> 3) << 4);
    const char* asrc = (const char*)(hs + ((size_t)(b * 32 + l) * 512 + i0) * D) + bso;
    const char* bsrc = (const char*)(dp + (size_t)(b * S + o0) * D) + bso;

#define SBAR() __builtin_amdgcn_sched_barrier(0)
#define BAR()  __builtin_amdgcn_s_barrier()

    // 4 gload_lds (512 thr x 16B = 8KB each = 64 rows): 256-row tile
#define A_GLOAD(tt) do {                                                        \
        _Pragma("unroll")                                                       \
        for (int q = 0; q < 4; ++q) {                                           \
            const int rg = q * 64 + wid * 8 + (lane >> 3);                      \
            __builtin_amdgcn_global_load_lds(                                   \
                (const __attribute__((address_space(1))) void*)(asrc +          \
                    ((size_t)rg * D + (size_t)(tt) * BK) * 2),                  \
                (__attribute__((address_space(3))) void*)                       \
                    (&Al[(tt) & 1][(q * 64 + wid * 8) * BK] + lane * 8),        \
                16, 0, 0);                                                      \
        }                                                                       \
    } while (0)

#define B_GLOAD(tt) do {                                                        \
        _Pragma("unroll")                                                       \
        for (int q = 0; q < 4; ++q) {                                           \
            const int rg = q * 64 + wid * 8 + (lane >> 3);                      \
            __builtin_amdgcn_global_load_lds(                                   \
                (const __attribute__((address_space(1))) void*)(bsrc +          \
                    ((size_t)rg * D + (size_t)(tt) * BK) * 2),                  \
                (__attribute__((address_space(3))) void*)                       \
                    (&Bl[(tt) & 1][(q * 64 + wid * 8) * BK] + lane * 8),        \
                16, 0, 0);                                                      \
        }                                                                       \
    } while (0)

    f32x4 acc[8][4] = {};
    bf16x8 bfr[4];

#define DSREAD_A(buf_, mh_, ks_, af_) do {                                      \
        const int cb = (ks_) * 64 + ((lane >> 4) << 4);                         \
        _Pragma("unroll")                                                       \
        for (int f = 0; f < 4; ++f) {                                           \
            const int row = wm * 128 + ((mh_) * 4 + f) * 16 + (lane & 15);      \
            af_[f] = *(const bf16x8*)&Al[buf_][row * BK + ((cb ^ ((row & 7) << 4)) >> 1)]; \
        }                                                                       \
    } while (0)

#define DSREAD_B(buf_, ks_) do {                                                \
        const int cb = (ks_) * 64 + ((lane >> 4) << 4);                         \
        _Pragma("unroll")                                                       \
        for (int f = 0; f < 4; ++f) {                                           \
            const int row = wn * 64 + f * 16 + (lane & 15);                     \
            bfr[f] = *(const bf16x8*)&Bl[buf_][row * BK + ((cb ^ ((row & 7) << 4)) >> 1)]; \
        }                                                                       \
    } while (0)

#define MFMA16(mh_, af_) do {                                                   \
        __builtin_amdgcn_s_setprio(1);                                          \
        _Pragma("unroll")                                                       \
        for (int m = 0; m < 4; ++m)                                             \
            _Pragma("unroll")                                                   \
            for (int n = 0; n < 4; ++n)                                         \
                acc[(mh_) * 4 + m][n] = __builtin_amdgcn_mfma_f32_16x16x32_bf16(\
                    af_[m], bfr[n], acc[(mh_) * 4 + m][n], 0, 0, 0);            \
        __builtin_amdgcn_s_setprio(0);                                          \
    } while (0)

    // ---- prologue: stage tile 0, full drain once
    A_GLOAD(0);
    B_GLOAD(0);
    SBAR();
    asm volatile("s_waitcnt vmcnt(0) lgkmcnt(0)" ::: "memory");
    SBAR();
    BAR();
    SBAR();

#pragma unroll
    for (int t = 0; t < NT; ++t) {
        const int c = t & 1;
        bf16x8 af[4];

        // ph0: (mh0, ks0); issue A(t+1)
        DSREAD_A(c, 0, 0, af); DSREAD_B(c, 0);
        if (t + 1 < NT) A_GLOAD(t + 1);
        SBAR(); BAR(); SBAR();
        MFMA16(0, af);
        SBAR(); BAR(); SBAR();

        // ph1: (mh1, ks0); issue B(t+1)
        DSREAD_A(c, 1, 0, af);
        if (t + 1 < NT) B_GLOAD(t + 1);
        SBAR(); BAR(); SBAR();
        MFMA16(1, af);
        SBAR(); BAR(); SBAR();

        // ph2: (mh0, ks1)
        DSREAD_A(c, 0, 1, af); DSREAD_B(c, 1);
        SBAR(); BAR(); SBAR();
        MFMA16(0, af);
        SBAR(); BAR(); SBAR();

        // ph3: (mh1, ks1); tile-end drain (gloads aged >=2 phases -> cheap)
        DSREAD_A(c, 1, 1, af);
        SBAR(); BAR(); SBAR();
        MFMA16(1, af);
        SBAR();
        if (t + 1 < NT) {
            asm volatile("s_waitcnt vmcnt(0)" ::: "memory");
            SBAR();
            BAR();
            SBAR();
        }
    }

    // ---- epilogue: C/D layout col=lane&15, row=(lane>>4)*4+r
    float* op = out + (size_t)(b * L + l) * S * S;
#pragma unroll
    for (int m = 0; m < 8; ++m) {
        const int row0 = i0 + wm * 128 + m * 16 + ((lane >> 4) << 2);
#pragma unroll
        for (int n = 0; n < 4; ++n) {
            const int col = o0 + wn * 64 + n * 16 + (lane & 15);
#pragma unroll
            for (int r = 0; r < 4; ++r)
                op[(size_t)(row0 + r) * S + col] = acc[m][n][r];
        }
    }

#undef SBAR
#undef BAR
#undef A_GLOAD
#undef B_GLOAD
#undef DSREAD_A
#undef DSREAD_B
#undef MFMA16
}

// ---------------- fallback (proven R1 kernel): used only if ws too small ------
__global__ __launch_bounds__(256, 2)
void bla_fb(const float* __restrict__ head, const float* __restrict__ dep,
            const float* __restrict__ U, float* __restrict__ out)
{
    constexpr int S = 512, D = 512, L = 32, BM = 128, BN = 128, BK = 64, NT = 8;
    __shared__ short Al[2][BM * BK];
    __shared__ short Bl[2][BN * BK];
    const int tid = threadIdx.x, lane = tid & 63, wid = tid >> 6;
    const int wm = wid >> 1, wn = wid & 1;
    const int swz = (blockIdx.x & 7) * ((int)gridDim.x >> 3) + (blockIdx.x >> 3);
    const int b = swz >> 9, rem = swz & 511;
    const int l = rem >> 4, it = (rem >> 2) & 3, ot = rem & 3;
    const int i0 = it * BM, o0 = ot * BN;
    const int srow = tid >> 3, scol = (tid & 7) * 8, swb = scol * 2;
    const float* hb = head + (size_t)(b * S + i0 + srow) * D + scol;
    const float* db = dep + (size_t)(b * S + o0 + srow) * D + scol;
    const float* ub = U + l * D + scol;
    f32x4 ra[4][2], rb[4][2], ru[2];
#define FSTAGE_LOAD(t) do { const int k0_ = (t) * BK;                              \
        ru[0] = *(const f32x4*)(ub + k0_); ru[1] = *(const f32x4*)(ub + k0_ + 4);  \
        _Pragma("unroll") for (int p_ = 0; p_ < 4; ++p_) {                         \
            ra[p_][0] = *(const f32x4*)(hb + k0_ + p_ * 32 * D);                   \
            ra[p_][1] = *(const f32x4*)(hb + k0_ + p_ * 32 * D + 4);               \
            rb[p_][0] = *(const f32x4*)(db + k0_ + p_ * 32 * D);                   \
            rb[p_][1] = *(const f32x4*)(db + k0_ + p_ * 32 * D + 4); } } while (0)
#define FSTAGE_WRITE(buf) do { _Pragma("unroll") for (int p_ = 0; p_ < 4; ++p_) {  \
            const int row_ = srow + p_ * 32; const int sb_ = swb ^ ((row_ & 7) << 4); \
            bf16x8 av_, bv_;                                                       \
            _Pragma("unroll") for (int q_ = 0; q_ < 2; ++q_)                       \
                _Pragma("unroll") for (int j_ = 0; j_ < 4; ++j_) {                 \
                    av_[q_ * 4 + j_] = bf16r(ra[p_][q_][j_] * ru[q_][j_]);         \
                    bv_[q_ * 4 + j_] = bf16r(rb[p_][q_][j_]); }                    \
            *(bf16x8*)&Al[buf][row_ * BK + (sb_ >> 1)] = av_;                      \
            *(bf16x8*)&Bl[buf][row_ * BK + (sb_ >> 1)] = bv_; } } while (0)
    f32x4 acc[4][4] = {};
    const int cbase = (lane >> 4) << 4, rsw = (lane & 7) << 4;
#define FCOMPUTE(buf) do { _Pragma("unroll") for (int ks_ = 0; ks_ < 2; ++ks_) {   \
            const int sb2_ = (ks_ * 64 + cbase) ^ rsw; bf16x8 af_[4], bfr_[4];     \
            _Pragma("unroll") for (int f_ = 0; f_ < 4; ++f_) {                     \
                af_[f_] = *(const bf16x8*)&Al[buf][(wm * 64 + f_ * 16 + (lane & 15)) * BK + (sb2_ >> 1)]; \
                bfr_[f_] = *(const bf16x8*)&Bl[buf][(wn * 64 + f_ * 16 + (lane & 15)) * BK + (sb2_ >> 1)]; } \
            _Pragma("unroll") for (int fm_ = 0; fm_ < 4; ++fm_)                    \
                _Pragma("unroll") for (int fn_ = 0; fn_ < 4; ++fn_)                \
                    acc[fm_][fn_] = __builtin_amdgcn_mfma_f32_16x16x32_bf16(       \
                        af_[fm_], bfr_[fn_], acc[fm_][fn_], 0, 0, 0); } } while (0)
    FSTAGE_LOAD(0); FSTAGE_WRITE(0); __syncthreads();
    int cur = 0;
#pragma unroll
    for (int t = 0; t < NT; ++t) {
        if (t + 1 < NT) FSTAGE_LOAD(t + 1);
        FCOMPUTE(cur);
        if (t + 1 < NT) FSTAGE_WRITE(cur ^ 1);
        __syncthreads();
        cur ^= 1;
    }
    float* op = out + (size_t)(b * L + l) * S * S;
#pragma unroll
    for (int fm = 0; fm < 4; ++fm) {
        const int row0 = i0 + wm * 64 + fm * 16 + ((lane >> 4) << 2);
#pragma unroll
        for (int fn = 0; fn < 4; ++fn) {
            const int col = o0 + wn * 64 + fn * 16 + (lane & 15);
#pragma unroll
            for (int r = 0; r < 4; ++r)
                op[(size_t)(row0 + r) * S + col] = acc[fm][fn][r];
        }
    }
#undef FSTAGE_LOAD
#undef FSTAGE_WRITE
#undef FCOMPUTE
}

extern "C" void kernel_launch(void* const* d_in, const int* in_sizes, int n_in,
                              void* d_out, int out_size, void* d_ws, size_t ws_size,
                              hipStream_t stream)
{
    const float* head = (const float*)d_in[0];
    const float* dep  = (const float*)d_in[1];
    const float* U    = (const float*)d_in[2];
    float* out        = (float*)d_out;

    const size_t nhs  = (size_t)8 * 32 * 512 * 512;   // 64M elems = 128MB bf16
    const size_t ndep = (size_t)8 * 512 * 512;        // 2M elems  = 4MB bf16
    const size_t need = (nhs + ndep) * 2;             // 132MB
    if (ws_size >= need) {
        short* hs = (short*)d_ws;
        short* dp = hs + nhs;
        // 8,388,608 hs-chunks + 262,144 dep-chunks = 8,650,752 threads
        prep_kernel<<<dim3(33792), dim3(256), 0, stream>>>(head, dep, U, hs, dp);
        bla_gemm12<<<dim3(1024), dim3(512), 0, stream>>>(hs, dp, out);
    } else {
        bla_fb<<<dim3(4096), dim3(256), 0, stream>>>(head, dep, U, out);
    }
}